// Round 2
// baseline (485.629 us; speedup 1.0000x reference)
//
#include <hip/hip_runtime.h>

// out[b][i][d] = sum_l x_i[b][l][d]
// B=512, D=128, L_i = 64*(i+1) for i=0..7.
//
// R2 design: persistent streaming waves. One wave per (b, i) output row;
// 4096 waves = 1024 blocks x 256 threads = 16 waves/CU -> the ENTIRE grid is
// co-resident (no CP re-dispatch churn; R1's 18432 one-shot blocks stalled at
// 70% occupancy). Each wave is a pure load->accumulate stream over its
// [L x 128] slab: no LDS, no barriers, no atomics, no zero-kernel -> the
// load phase is ~95% of wave lifetime (R1 spent >half of each block's life
// in setup/drain/barrier/atomic, capping HBM at 1.85 TB/s).
//
// Ragged lengths are balanced at block granularity: the 4 waves of a block
// handle tensor pairs (p, 7-p) so every block sums exactly 1152 rows.
//
// Per-iteration addressing: float4 index = lb*32 + u*64 + lane, u=0..7 ->
// eight contiguous 1 KB wave-loads covering an 8 KB window. Lane l
// accumulates column (l&31), row-parity (l>>5); one shfl_down(32) merges the
// two parities; lanes 0..31 store the 512 B output row.

struct SumCatArgs {
    const float* x[8];
    int L[8];
};

__global__ __launch_bounds__(256) void fuse_sum_cat_kernel(
    SumCatArgs args, float* __restrict__ out) {
    const int wid  = threadIdx.x >> 6;   // wave 0..3 within block
    const int lane = threadIdx.x & 63;

    // Block bk covers batch b = bk>>1; its 4 waves cover tensor set
    // {0,7,1,6} (bk even) or {2,5,3,4} (bk odd): each block = 1152 rows.
    const int bk = blockIdx.x;
    const int b  = bk >> 1;
    const int p  = (bk & 1) * 2 + (wid >> 1);     // pair index 0..3
    const int i  = (wid & 1) ? (7 - p) : p;       // tensor index
    const int L  = args.L[i];

    const float4* __restrict__ xr =
        (const float4*)args.x[i] + (size_t)b * (size_t)L * 32;

    float4 a0 = make_float4(0.f, 0.f, 0.f, 0.f);
    float4 a1 = make_float4(0.f, 0.f, 0.f, 0.f);

    // L is a multiple of 64 -> 16-row windows divide evenly (4..32 iters).
    for (int lb = 0; lb < L; lb += 16) {
        const float4* __restrict__ w = xr + (size_t)lb * 32;
        float4 v[8];
#pragma unroll
        for (int u = 0; u < 8; ++u) v[u] = w[u * 64 + lane];
#pragma unroll
        for (int u = 0; u < 8; u += 2) {
            a0.x += v[u].x;     a0.y += v[u].y;
            a0.z += v[u].z;     a0.w += v[u].w;
            a1.x += v[u + 1].x; a1.y += v[u + 1].y;
            a1.z += v[u + 1].z; a1.w += v[u + 1].w;
        }
    }

    float4 acc = make_float4(a0.x + a1.x, a0.y + a1.y,
                             a0.z + a1.z, a0.w + a1.w);

    // Merge row-parity halves: lane l (<32) += lane l+32. Same column.
    acc.x += __shfl_down(acc.x, 32, 64);
    acc.y += __shfl_down(acc.y, 32, 64);
    acc.z += __shfl_down(acc.z, 32, 64);
    acc.w += __shfl_down(acc.w, 32, 64);

    if (lane < 32) {
        float4* __restrict__ orow =
            (float4*)(out + ((size_t)b * 8 + i) * 128);
        orow[lane] = acc;
    }
}

extern "C" void kernel_launch(void* const* d_in, const int* in_sizes, int n_in,
                              void* d_out, int out_size, void* d_ws, size_t ws_size,
                              hipStream_t stream) {
    (void)d_ws; (void)ws_size; (void)out_size; (void)n_in;

    SumCatArgs args;
    for (int i = 0; i < 8; ++i) {
        args.x[i] = (const float*)d_in[i];
        args.L[i] = in_sizes[i] / (512 * 128);  // B*D = 65536
    }

    // 1024 blocks x 256 threads = 4096 waves: one per (b, i), all resident.
    fuse_sum_cat_kernel<<<1024, 256, 0, stream>>>(args, (float*)d_out);
}

// Round 3
// 485.216 us; speedup vs baseline: 1.0009x; 1.0009x over previous
//
#include <hip/hip_runtime.h>

// out[b][i][d] = sum_l x_i[b][l][d];  B=512, D=128, L_i = 64*(i+1).
//
// R3: wave-uniform work + forced-deep memory pipeline.
//
// Grid: 1024 blocks (= 512 batches x 2 halves) x 256 threads = 4096 waves,
// exactly 4 blocks/CU -> whole grid co-resident. Block (b,h) owns the
// concatenation of 4 tensors: h=0 -> {0,7,1,6} (rows 64+512+128+448=1152),
// h=1 -> {2,5,3,4} (192+384+256+320=1152). Wave w owns rows [288w, 288w+288)
// of that block-space: EVERY wave in the grid processes exactly 18 chunks of
// 16 rows (R2's waves had 1:8 length spread -> occupancy decayed to 32%).
// Waves flush per-tensor partials into LDS (float atomicAdd, ~2.5 flushes
// per wave); block stores 4 output rows at the end.
//
// Memory pipeline: two named float4[8] buffers, next chunk's 8x1KB loads
// issued BEFORE consuming the current buffer, sched_barrier(0) pinning the
// load group above the adds. R0-R2 all compiled to VGPR_Count<=28 (<=4 loads
// in flight); this forces 8-16 KB outstanding per wave.

struct SumCatArgs {
    const float* x[8];
    int L[8];
};

__device__ __forceinline__ void load_chunk(float4 (&v)[8],
                                           const float4* __restrict__ base,
                                           int c, int lane) {
#pragma unroll
    for (int u = 0; u < 8; ++u)
        v[u] = base[(size_t)c * 512 + u * 64 + lane];
    // Pin: all 8 loads issue before anything below this point.
    __builtin_amdgcn_sched_barrier(0);
}

__device__ __forceinline__ void acc_chunk(float4& p0, float4& p1,
                                          const float4 (&v)[8]) {
#pragma unroll
    for (int u = 0; u < 8; u += 2) {
        p0.x += v[u].x;     p0.y += v[u].y;
        p0.z += v[u].z;     p0.w += v[u].w;
        p1.x += v[u + 1].x; p1.y += v[u + 1].y;
        p1.z += v[u + 1].z; p1.w += v[u + 1].w;
    }
}

__global__ __launch_bounds__(256, 4) void fuse_sum_cat_kernel(
    SumCatArgs args, float* __restrict__ out) {
    const int lane = threadIdx.x & 63;
    const int wid  = threadIdx.x >> 6;
    const int bk   = blockIdx.x;
    const int b    = bk >> 1;
    const int h    = bk & 1;

    __shared__ float oacc[4][128];
    ((float2*)&oacc[0][0])[threadIdx.x] = make_float2(0.f, 0.f);
    __syncthreads();

    // Tensor ids for the 4 segments (compile-time kernarg indices per arm).
    const int t0 = h ? 2 : 0, t1 = h ? 5 : 7, t2 = h ? 3 : 1, t3 = h ? 4 : 6;
    const float* __restrict__ xp0 = h ? args.x[2] : args.x[0];
    const float* __restrict__ xp1 = h ? args.x[5] : args.x[7];
    const float* __restrict__ xp2 = h ? args.x[3] : args.x[1];
    const float* __restrict__ xp3 = h ? args.x[4] : args.x[6];
    const int L0 = h ? args.L[2] : args.L[0];
    const int L1 = h ? args.L[5] : args.L[7];
    const int L2 = h ? args.L[3] : args.L[1];
    const int L3 = h ? args.L[4] : args.L[6];

    const int pre1 = L0, pre2 = pre1 + L1, pre3 = pre2 + L2, pre4 = pre3 + L3;

    const int r0 = wid * 288;
    const int r1 = r0 + 288;

#define PROCESS_SEG(S, XP, LS, PS, PE)                                        \
    {                                                                         \
        const int lo = r0 > (PS) ? r0 : (PS);                                 \
        const int hi = r1 < (PE) ? r1 : (PE);                                 \
        if (hi > lo) {                                                        \
            const float4* __restrict__ base =                                 \
                (const float4*)(XP) +                                         \
                ((size_t)b * (size_t)(LS) + (size_t)(lo - (PS))) * 32;        \
            const int n = (hi - lo) >> 4;                                     \
            float4 A[8], B[8];                                                \
            float4 p0 = make_float4(0.f, 0.f, 0.f, 0.f);                      \
            float4 p1 = make_float4(0.f, 0.f, 0.f, 0.f);                      \
            load_chunk(A, base, 0, lane);                                     \
            int c = 1;                                                        \
            for (; c + 1 < n; c += 2) {                                       \
                load_chunk(B, base, c, lane);                                 \
                acc_chunk(p0, p1, A);                                         \
                load_chunk(A, base, c + 1, lane);                             \
                acc_chunk(p0, p1, B);                                         \
            }                                                                 \
            if (c < n) {                                                      \
                load_chunk(B, base, c, lane);                                 \
                acc_chunk(p0, p1, A);                                         \
                acc_chunk(p0, p1, B);                                         \
            } else {                                                          \
                acc_chunk(p0, p1, A);                                         \
            }                                                                 \
            float4 acc = make_float4(p0.x + p1.x, p0.y + p1.y,                \
                                     p0.z + p1.z, p0.w + p1.w);               \
            acc.x += __shfl_down(acc.x, 32, 64);                              \
            acc.y += __shfl_down(acc.y, 32, 64);                              \
            acc.z += __shfl_down(acc.z, 32, 64);                              \
            acc.w += __shfl_down(acc.w, 32, 64);                              \
            if (lane < 32) {                                                  \
                atomicAdd(&oacc[S][lane * 4 + 0], acc.x);                     \
                atomicAdd(&oacc[S][lane * 4 + 1], acc.y);                     \
                atomicAdd(&oacc[S][lane * 4 + 2], acc.z);                     \
                atomicAdd(&oacc[S][lane * 4 + 3], acc.w);                     \
            }                                                                 \
        }                                                                     \
    }

    PROCESS_SEG(0, xp0, L0, 0,    pre1)
    PROCESS_SEG(1, xp1, L1, pre1, pre2)
    PROCESS_SEG(2, xp2, L2, pre2, pre3)
    PROCESS_SEG(3, xp3, L3, pre3, pre4)
#undef PROCESS_SEG

    __syncthreads();

    // Store the block's 4 output rows: wave w stores row w (float2/lane).
    const int rl = wid;
    const int d  = lane * 2;
    const int ti = rl == 0 ? t0 : rl == 1 ? t1 : rl == 2 ? t2 : t3;
    float2 v = *(const float2*)&oacc[rl][d];
    *(float2*)&out[((size_t)b * 8 + ti) * 128 + d] = v;
}

extern "C" void kernel_launch(void* const* d_in, const int* in_sizes, int n_in,
                              void* d_out, int out_size, void* d_ws, size_t ws_size,
                              hipStream_t stream) {
    (void)d_ws; (void)ws_size; (void)out_size; (void)n_in;

    SumCatArgs args;
    for (int i = 0; i < 8; ++i) {
        args.x[i] = (const float*)d_in[i];
        args.L[i] = in_sizes[i] / (512 * 128);  // B*D = 65536
    }

    // 512 batches x 2 halves; 4 waves/block, each wave = 18 uniform chunks.
    fuse_sum_cat_kernel<<<1024, 256, 0, stream>>>(args, (float*)d_out);
}